// Round 1
// baseline (2376.766 us; speedup 1.0000x reference)
//
#include <hip/hip_runtime.h>
#include <math.h>

#define NN 50000
#define EE 250000
#define TTT 6
#define DD 256
#define HH 4
#define CC 64
#define KDIM 64

#define TM 64
#define TN 64
#define TKK 32

// ---------------- fp32 tiled GEMM: C[n,m] = op(A[n,:]) @ B[:,m] -------------
// op = 0: A row scaled by rowscale[n];  op = 1: relu(A)
__global__ __launch_bounds__(256) void gemm_k(
    const float* __restrict__ A, const float* __restrict__ B,
    float* __restrict__ Cout, const float* __restrict__ rowscale,
    int op, int nrows)
{
    __shared__ __align__(16) float As[TKK][TM + 4];
    __shared__ __align__(16) float Bs[TKK][TN + 4];
    int tid = threadIdx.x;
    int row0 = blockIdx.x * TM;
    int col0 = blockIdx.y * TN;
    int tx = tid & 15, ty = tid >> 4;
    float acc[4][4] = {};
    for (int k0 = 0; k0 < DD; k0 += TKK) {
        for (int i = tid; i < TM * TKK; i += 256) {
            int r = i / TKK, k = i % TKK;
            int gr = row0 + r;
            float v = 0.f;
            if (gr < nrows) {
                v = A[(size_t)gr * DD + k0 + k];
                if (op == 0) v *= rowscale[gr];
                else v = fmaxf(v, 0.f);
            }
            As[k][r] = v;
        }
        for (int i = tid; i < TKK * TN; i += 256) {
            int k = i / TN, m = i % TN;
            Bs[k][m] = B[(size_t)(k0 + k) * DD + col0 + m];
        }
        __syncthreads();
        #pragma unroll
        for (int kk = 0; kk < TKK; ++kk) {
            float4 a4 = *(const float4*)&As[kk][ty * 4];
            float4 b4 = *(const float4*)&Bs[kk][tx * 4];
            float av[4] = {a4.x, a4.y, a4.z, a4.w};
            float bv[4] = {b4.x, b4.y, b4.z, b4.w};
            #pragma unroll
            for (int i2 = 0; i2 < 4; ++i2)
                #pragma unroll
                for (int j = 0; j < 4; ++j)
                    acc[i2][j] = fmaf(av[i2], bv[j], acc[i2][j]);
        }
        __syncthreads();
    }
    #pragma unroll
    for (int i2 = 0; i2 < 4; ++i2) {
        int gr = row0 + ty * 4 + i2;
        if (gr < nrows) {
            float4 o = {acc[i2][0], acc[i2][1], acc[i2][2], acc[i2][3]};
            *(float4*)&Cout[(size_t)gr * DD + col0 + tx * 4] = o;
        }
    }
}

// -------- edge pass A+B: e = sum_c a*leaky(hd[dst]+hs[src]); p = exp(e); den += p
// one wave (64 lanes = C) per edge
__global__ __launch_bounds__(256) void edge_pAB(
    const float* __restrict__ hs, const float* __restrict__ hd,
    const int* __restrict__ src, const int* __restrict__ dst,
    const float* __restrict__ avec, float* __restrict__ pbuf,
    float* __restrict__ den, int nedges)
{
    int lane = threadIdx.x & 63;
    int e = (int)((blockIdx.x * 256 + threadIdx.x) >> 6);
    if (e >= nedges) return;
    int s = src[e], d = dst[e];
    const float* prs = hs + (size_t)s * DD;
    const float* prd = hd + (size_t)d * DD;
    #pragma unroll
    for (int h = 0; h < HH; ++h) {
        float x = prd[h * CC + lane] + prs[h * CC + lane];
        x = x > 0.f ? x : 0.2f * x;
        float v = avec[h * CC + lane] * x;
        #pragma unroll
        for (int off = 32; off; off >>= 1) v += __shfl_xor(v, off, 64);
        if (lane == 0) {
            float p = expf(v);   // no max-subtraction: |e| small, exp safe; alpha identical
            pbuf[(size_t)e * HH + h] = p;
            atomicAdd(&den[d * HH + h], p);
        }
    }
}

// -------- edge pass C: hout[dst] += (p/den)*edge_mask * hs[src]
__global__ __launch_bounds__(256) void edge_pC(
    const float* __restrict__ hs, const float* __restrict__ pbuf,
    const int* __restrict__ src, const int* __restrict__ dst,
    const float* __restrict__ den, const float* __restrict__ emask,
    float* __restrict__ hout, int nedges)
{
    int lane = threadIdx.x & 63;
    int e = (int)((blockIdx.x * 256 + threadIdx.x) >> 6);
    if (e >= nedges) return;
    int s = src[e], d = dst[e];
    float ew = emask[e];
    const float* prs = hs + (size_t)s * DD;
    float* po = hout + (size_t)d * DD;
    #pragma unroll
    for (int h = 0; h < HH; ++h) {
        float coef = ew * pbuf[(size_t)e * HH + h] / (den[d * HH + h] + 1e-16f);
        atomicAdd(&po[h * CC + lane], coef * prs[h * CC + lane]);
    }
}

// -------- per-timestep mean of edge_attr -> esum[t] (double, divide later)
__global__ __launch_bounds__(256) void edge_mean_k(
    const float* __restrict__ eattr, double* __restrict__ esum, int nedges)
{
    int i = blockIdx.x * 256 + threadIdx.x;
    #pragma unroll
    for (int t = 0; t < TTT; ++t) {
        float v = (i < nedges) ? eattr[(size_t)t * nedges + i] : 0.f;
        #pragma unroll
        for (int off = 32; off; off >>= 1) v += __shfl_xor(v, off, 64);
        if ((threadIdx.x & 63) == 0) atomicAdd(&esum[t], (double)v);
    }
}

// -------- fused assignment softmax + pooling: xpool[k,d] += softmax_k(x@Wa)[n,k]*x[n,d]
__global__ __launch_bounds__(256) void assign_pool_k(
    const float* __restrict__ x, const float* __restrict__ Wa,
    float* __restrict__ xpool, int nrows)
{
    __shared__ float Was[DD * KDIM];   // 64 KB, Wa[d][k]
    __shared__ float xrow[4][DD];      // 4 KB
    __shared__ float part[4][4][KDIM]; // [chunk][node][k]
    __shared__ float ssh[4][KDIM];
    int tid = threadIdx.x;
    for (int i = tid; i < DD * KDIM; i += 256) Was[i] = Wa[i];
    float pool[KDIM];
    #pragma unroll
    for (int k = 0; k < KDIM; ++k) pool[k] = 0.f;
    __syncthreads();
    int k = tid & 63, chunk = tid >> 6;
    for (int n0 = blockIdx.x * 4; n0 < nrows; n0 += gridDim.x * 4) {
        for (int i = tid; i < 4 * DD; i += 256) {
            int j = i >> 8, d = i & 255;
            int n = n0 + j;
            xrow[j][d] = (n < nrows) ? x[(size_t)n * DD + d] : 0.f;
        }
        __syncthreads();
        #pragma unroll
        for (int j = 0; j < 4; ++j) {
            float p = 0.f;
            #pragma unroll
            for (int dd = 0; dd < 64; ++dd) {
                int d = chunk * 64 + dd;
                p = fmaf(xrow[j][d], Was[d * KDIM + k], p);
            }
            part[chunk][j][k] = p;
        }
        __syncthreads();
        {
            int j = chunk;   // wave j handles node n0+j
            float v = part[0][j][k] + part[1][j][k] + part[2][j][k] + part[3][j][k];
            float mx = v;
            #pragma unroll
            for (int off = 32; off; off >>= 1) mx = fmaxf(mx, __shfl_xor(mx, off, 64));
            float ev = expf(v - mx);
            float sm = ev;
            #pragma unroll
            for (int off = 32; off; off >>= 1) sm += __shfl_xor(sm, off, 64);
            ssh[j][k] = ev / sm;
        }
        __syncthreads();
        #pragma unroll
        for (int j = 0; j < 4; ++j) {
            if (n0 + j < nrows) {
                float xv = xrow[j][tid];
                #pragma unroll
                for (int kk = 0; kk < KDIM; ++kk)
                    pool[kk] = fmaf(ssh[j][kk], xv, pool[kk]);
            }
        }
        __syncthreads();
    }
    for (int kk = 0; kk < KDIM; ++kk)
        atomicAdd(&xpool[kk * DD + tid], pool[kk]);
}

// -------- final classifier: logits[k] = xpool[k,:]@Wcls[0:D] + agg_edge@Wcls[D:] + b
__global__ void final_k(const float* __restrict__ xpool, const double* __restrict__ esum,
                        const float* __restrict__ Wcls, const float* __restrict__ bcls,
                        float* __restrict__ out)
{
    int kk = threadIdx.x;   // 0..63
    double acc = 0.0;
    for (int d = 0; d < DD; ++d)
        acc += (double)xpool[kk * DD + d] * (double)Wcls[d];
    for (int t = 0; t < TTT; ++t)
        acc += (esum[t] / (double)EE) * (double)Wcls[DD + t];
    acc += (double)bcls[0];
    out[kk] = (float)(1.0 / (1.0 + exp(-acc)));
}

extern "C" void kernel_launch(void* const* d_in, const int* in_sizes, int n_in,
                              void* d_out, int out_size, void* d_ws, size_t ws_size,
                              hipStream_t stream)
{
    const float* x_pkg   = (const float*)d_in[0];
    const float* x_dst   = (const float*)d_in[1];
    const int*   eindex  = (const int*)d_in[2];
    const float* eattr   = (const float*)d_in[3];
    const float* nmask   = (const float*)d_in[4];
    const float* emask   = (const float*)d_in[5];
    const float* W1s     = (const float*)d_in[6];
    const float* W1d     = (const float*)d_in[7];
    const float* a1      = (const float*)d_in[8];
    const float* W2s     = (const float*)d_in[9];
    const float* W2d     = (const float*)d_in[10];
    const float* a2      = (const float*)d_in[11];
    const float* Wassign = (const float*)d_in[12];
    const float* Wcls    = (const float*)d_in[13];
    const float* bcls    = (const float*)d_in[14];
    float* out = (float*)d_out;

    const int t = TTT - 1;  // only t=5 feeds the output (h2[-1]); h1[0..4]/h2[0..4] are dead
    const int* src5 = eindex + (size_t)t * 2 * EE;
    const int* dst5 = src5 + EE;
    const float* xdst5 = x_dst + (size_t)t * NN * DD;
    const float* W1s5 = W1s + (size_t)t * DD * HH * CC;
    const float* W1d5 = W1d + (size_t)t * DD * HH * CC;
    const float* a15  = a1 + (size_t)t * HH * CC;
    const float* W2s5 = W2s + (size_t)t * DD * HH * CC;
    const float* W2d5 = W2d + (size_t)t * DD * HH * CC;
    const float* a25  = a2 + (size_t)t * HH * CC;

    float* hs    = (float*)d_ws;                 // N*256
    float* hd    = hs + (size_t)NN * DD;         // N*256
    float* hbuf  = hd + (size_t)NN * DD;         // N*256 (h1 then h2)
    float* pbuf  = hbuf + (size_t)NN * DD;       // E*H
    float* dbuf  = pbuf + (size_t)EE * HH;       // N*H
    float* xpool = dbuf + (size_t)NN * HH;       // K*D
    double* esum = (double*)(xpool + KDIM * DD); // T doubles

    dim3 gemm_grid((NN + TM - 1) / TM, DD / TN);
    int edge_blocks = (EE + 3) / 4;          // 1 wave per edge, 4 waves/block
    int mean_blocks = (EE + 255) / 256;

    // ---- init ----
    hipMemsetAsync(dbuf, 0, (size_t)NN * HH * sizeof(float), stream);
    hipMemsetAsync(hbuf, 0, (size_t)NN * DD * sizeof(float), stream);
    hipMemsetAsync(xpool, 0, (size_t)KDIM * DD * sizeof(float), stream);
    hipMemsetAsync(esum, 0, TTT * sizeof(double), stream);

    edge_mean_k<<<mean_blocks, 256, 0, stream>>>(eattr, esum, EE);

    // ---- layer 1 (t=5): hs = (x_pkg*nm)@W1s, hd = (x_dst[5]*nm)@W1d ----
    gemm_k<<<gemm_grid, 256, 0, stream>>>(x_pkg, W1s5, hs, nmask, 0, NN);
    gemm_k<<<gemm_grid, 256, 0, stream>>>(xdst5, W1d5, hd, nmask, 0, NN);
    edge_pAB<<<edge_blocks, 256, 0, stream>>>(hs, hd, src5, dst5, a15, pbuf, dbuf, EE);
    edge_pC<<<edge_blocks, 256, 0, stream>>>(hs, pbuf, src5, dst5, dbuf, emask, hbuf, EE);

    // ---- layer 2: hd = relu(h1)@W2d, hs = relu(x_pkg)@W2s ----
    gemm_k<<<gemm_grid, 256, 0, stream>>>(hbuf, W2d5, hd, nullptr, 1, NN);
    gemm_k<<<gemm_grid, 256, 0, stream>>>(x_pkg, W2s5, hs, nullptr, 1, NN);
    hipMemsetAsync(dbuf, 0, (size_t)NN * HH * sizeof(float), stream);
    hipMemsetAsync(hbuf, 0, (size_t)NN * DD * sizeof(float), stream);
    edge_pAB<<<edge_blocks, 256, 0, stream>>>(hs, hd, src5, dst5, a25, pbuf, dbuf, EE);
    edge_pC<<<edge_blocks, 256, 0, stream>>>(hs, pbuf, src5, dst5, dbuf, emask, hbuf, EE);

    // ---- assignment softmax + pooling + classifier ----
    assign_pool_k<<<120, 256, 0, stream>>>(hbuf, Wassign, xpool, NN);
    final_k<<<1, 64, 0, stream>>>(xpool, esum, Wcls, bcls, out);
}

// Round 3
// 1441.786 us; speedup vs baseline: 1.6485x; 1.6485x over previous
//
#include <hip/hip_runtime.h>
#include <math.h>

#define NN 50000
#define EE 250000
#define TTT 6
#define DD 256
#define HH 4
#define CC 64
#define KDIM 64

// ---------------- fp32 tiled GEMM 128x128x16, 8x8 micro-tile ----------------
// C[n,m] = op(A[n,:]) @ B[:,m];  op=0: A row scaled by rowscale[n]; op=1: relu(A)
#define GM 128
#define GN 128
#define GK 16

__global__ __launch_bounds__(256) void gemm128_k(
    const float* __restrict__ A, const float* __restrict__ B,
    float* __restrict__ Cout, const float* __restrict__ rowscale,
    int op, int nrows)
{
    __shared__ __align__(16) float As[GK][GM + 4];
    __shared__ __align__(16) float Bs[GK][GN + 4];
    int tid = threadIdx.x;
    int row0 = blockIdx.x * GM;
    int col0 = blockIdx.y * GN;
    int tx = tid & 15, ty = tid >> 4;
    float acc[8][8] = {};
    for (int k0 = 0; k0 < DD; k0 += GK) {
        // stage A: 128 rows x 16 k = 512 float4
        #pragma unroll
        for (int li = 0; li < 2; ++li) {
            int i = tid + li * 256;
            int r = i >> 2;
            int kq = (i & 3) * 4;
            int gr = row0 + r;
            float4 v = make_float4(0.f, 0.f, 0.f, 0.f);
            if (gr < nrows) {
                v = *(const float4*)&A[(size_t)gr * DD + k0 + kq];
                if (op == 0) {
                    float s = rowscale[gr];
                    v.x *= s; v.y *= s; v.z *= s; v.w *= s;
                } else {
                    v.x = fmaxf(v.x, 0.f); v.y = fmaxf(v.y, 0.f);
                    v.z = fmaxf(v.z, 0.f); v.w = fmaxf(v.w, 0.f);
                }
            }
            As[kq + 0][r] = v.x; As[kq + 1][r] = v.y;
            As[kq + 2][r] = v.z; As[kq + 3][r] = v.w;
        }
        // stage B: 16 k x 128 cols = 512 float4
        #pragma unroll
        for (int li = 0; li < 2; ++li) {
            int i = tid + li * 256;
            int k = i >> 5;
            int m = (i & 31) * 4;
            *(float4*)&Bs[k][m] = *(const float4*)&B[(size_t)(k0 + k) * DD + col0 + m];
        }
        __syncthreads();
        #pragma unroll
        for (int kk = 0; kk < GK; ++kk) {
            float a[8], b[8];
            *(float4*)&a[0] = *(const float4*)&As[kk][ty * 4];
            *(float4*)&a[4] = *(const float4*)&As[kk][64 + ty * 4];
            *(float4*)&b[0] = *(const float4*)&Bs[kk][tx * 4];
            *(float4*)&b[4] = *(const float4*)&Bs[kk][64 + tx * 4];
            #pragma unroll
            for (int i2 = 0; i2 < 8; ++i2)
                #pragma unroll
                for (int j = 0; j < 8; ++j)
                    acc[i2][j] = fmaf(a[i2], b[j], acc[i2][j]);
        }
        __syncthreads();
    }
    #pragma unroll
    for (int i2 = 0; i2 < 8; ++i2) {
        int gr = row0 + ((i2 < 4) ? (ty * 4 + i2) : (64 + ty * 4 + (i2 - 4)));
        if (gr < nrows) {
            float4 o0 = {acc[i2][0], acc[i2][1], acc[i2][2], acc[i2][3]};
            float4 o1 = {acc[i2][4], acc[i2][5], acc[i2][6], acc[i2][7]};
            *(float4*)&Cout[(size_t)gr * DD + col0 + tx * 4] = o0;
            *(float4*)&Cout[(size_t)gr * DD + col0 + 64 + tx * 4] = o1;
        }
    }
}

// ---------------- CSR build: count, scan, scatter ----------------
__global__ __launch_bounds__(256) void count_k(const int* __restrict__ dst,
                                               int* __restrict__ deg, int nedges)
{
    int e = blockIdx.x * 256 + threadIdx.x;
    if (e < nedges) atomicAdd(&deg[dst[e]], 1);
}

__global__ __launch_bounds__(1024) void scan_k(const int* __restrict__ deg,
                                               int* __restrict__ offs)
{
    __shared__ int part[1024];
    int tid = threadIdx.x;
    const int CH = (NN + 1023) / 1024;
    int base = tid * CH;
    int s = 0;
    for (int i = 0; i < CH; ++i)
        if (base + i < NN) s += deg[base + i];
    part[tid] = s;
    __syncthreads();
    for (int off = 1; off < 1024; off <<= 1) {
        int v = (tid >= off) ? part[tid - off] : 0;
        __syncthreads();
        part[tid] += v;
        __syncthreads();
    }
    int run = part[tid] - s;   // exclusive prefix of this chunk
    for (int i = 0; i < CH; ++i) {
        if (base + i < NN) { offs[base + i] = run; run += deg[base + i]; }
    }
    if (tid == 1023) offs[NN] = part[1023];
}

__global__ __launch_bounds__(256) void scatter_k(const int* __restrict__ dst,
                                                 const int* __restrict__ offs,
                                                 int* __restrict__ cursor,
                                                 int* __restrict__ eord, int nedges)
{
    int e = blockIdx.x * 256 + threadIdx.x;
    if (e < nedges) {
        int d = dst[e];
        int p = atomicAdd(&cursor[d], 1);
        eord[offs[d] + p] = e;
    }
}

// ------------- fused GATv2 edge pass: one wave per dst node, no atomics -----
__global__ __launch_bounds__(256) void edge_fused_k(
    const float* __restrict__ hs, const float* __restrict__ hd,
    const int* __restrict__ src, const float* __restrict__ emask,
    const int* __restrict__ eord, const int* __restrict__ offs,
    const float* __restrict__ avec, float* __restrict__ hout)
{
    int lane = threadIdx.x & 63;
    int n = (int)((blockIdx.x * 256 + threadIdx.x) >> 6);
    if (n >= NN) return;
    float hdv[HH], av[HH], den[HH], accv[HH];
    #pragma unroll
    for (int h = 0; h < HH; ++h) {
        hdv[h] = hd[(size_t)n * DD + h * CC + lane];
        av[h] = avec[h * CC + lane];
        den[h] = 0.f; accv[h] = 0.f;
    }
    int b = offs[n], e2 = offs[n + 1];
    for (int idx = b; idx < e2; ++idx) {
        int e = eord[idx];
        int s = src[e];
        float ew = emask[e];
        const float* prs = hs + (size_t)s * DD;
        #pragma unroll
        for (int h = 0; h < HH; ++h) {
            float hsv = prs[h * CC + lane];
            float xx = hdv[h] + hsv;
            xx = xx > 0.f ? xx : 0.2f * xx;
            float v = av[h] * xx;
            #pragma unroll
            for (int off = 32; off; off >>= 1) v += __shfl_xor(v, off, 64);
            float p = expf(v);   // |e-score| small: exp safe; alpha identical w/o max-sub
            den[h] += p;
            accv[h] = fmaf(p * ew, hsv, accv[h]);
        }
    }
    #pragma unroll
    for (int h = 0; h < HH; ++h)
        hout[(size_t)n * DD + h * CC + lane] = accv[h] / (den[h] + 1e-16f);
}

// -------- per-timestep mean of edge_attr -> esum[t] (double) ----------------
__global__ __launch_bounds__(256) void edge_mean_k(
    const float* __restrict__ eattr, double* __restrict__ esum, int nedges)
{
    int i = blockIdx.x * 256 + threadIdx.x;
    #pragma unroll
    for (int t = 0; t < TTT; ++t) {
        float v = (i < nedges) ? eattr[(size_t)t * nedges + i] : 0.f;
        #pragma unroll
        for (int off = 32; off; off >>= 1) v += __shfl_xor(v, off, 64);
        if ((threadIdx.x & 63) == 0) atomicAdd(&esum[t], (double)v);
    }
}

// ---- fused assign-softmax + pooled classifier reduction --------------------
// logit[k] += sum_{n in tile} softmax_k(x[n]@Wa) * (x[n]@wcls)
#define AM 64
#define AK 32
__global__ __launch_bounds__(256) void assign_reduce_k(
    const float* __restrict__ x, const float* __restrict__ Wa,
    const float* __restrict__ wcls, float* __restrict__ logit_acc, int nrows)
{
    __shared__ __align__(16) float As[AK][AM + 4];
    __shared__ __align__(16) float Bs[AK][KDIM];
    __shared__ float wc[DD];
    __shared__ float Ps[AM][KDIM + 1];
    __shared__ float zp[4][AM];
    __shared__ float zsh[AM], rs[AM];
    int tid = threadIdx.x;
    int row0 = blockIdx.x * AM;
    int tx = tid & 15, ty = tid >> 4;
    for (int i = tid; i < DD; i += 256) wc[i] = wcls[i];
    float acc[4][4] = {};
    float zacc = 0.f;
    int node = tid & 63, part = tid >> 6;
    for (int k0 = 0; k0 < DD; k0 += AK) {
        for (int i = tid; i < AM * AK; i += 256) {
            int r = i / AK, k = i % AK;
            int gr = row0 + r;
            As[k][r] = (gr < nrows) ? x[(size_t)gr * DD + k0 + k] : 0.f;
        }
        for (int i = tid; i < AK * KDIM; i += 256) {
            int k = i >> 6, m = i & 63;
            Bs[k][m] = Wa[(size_t)(k0 + k) * KDIM + m];
        }
        __syncthreads();
        #pragma unroll
        for (int kk = 0; kk < AK; ++kk) {
            float4 a4 = *(const float4*)&As[kk][ty * 4];
            float4 b4 = *(const float4*)&Bs[kk][tx * 4];
            float av[4] = {a4.x, a4.y, a4.z, a4.w};
            float bv[4] = {b4.x, b4.y, b4.z, b4.w};
            #pragma unroll
            for (int i2 = 0; i2 < 4; ++i2)
                #pragma unroll
                for (int j = 0; j < 4; ++j)
                    acc[i2][j] = fmaf(av[i2], bv[j], acc[i2][j]);
        }
        #pragma unroll
        for (int kk = part * 8; kk < part * 8 + 8; ++kk)
            zacc = fmaf(As[kk][node], wc[k0 + kk], zacc);
        __syncthreads();
    }
    #pragma unroll
    for (int i2 = 0; i2 < 4; ++i2)
        #pragma unroll
        for (int j = 0; j < 4; ++j)
            Ps[ty * 4 + i2][tx * 4 + j] = acc[i2][j];
    zp[part][node] = zacc;
    __syncthreads();
    if (tid < AM) {
        float z = zp[0][tid] + zp[1][tid] + zp[2][tid] + zp[3][tid];
        zsh[tid] = z;
        float m = -1e30f;
        for (int k = 0; k < KDIM; ++k) m = fmaxf(m, Ps[tid][k]);
        float s = 0.f;
        for (int k = 0; k < KDIM; ++k) {
            float v = expf(Ps[tid][k] - m);
            Ps[tid][k] = v;
            s += v;
        }
        rs[tid] = s;
    }
    __syncthreads();
    if (tid < KDIM) {
        float t = 0.f;
        for (int n = 0; n < AM; ++n)
            t += Ps[n][tid] / rs[n] * zsh[n];
        atomicAdd(&logit_acc[tid], t);
    }
}

// -------- final: out[k] = sigmoid(logit[k] + agg_edge@Wcls[D:] + b) ---------
__global__ void final_k(const float* __restrict__ logit, const double* __restrict__ esum,
                        const float* __restrict__ Wcls, const float* __restrict__ bcls,
                        float* __restrict__ out)
{
    int k = threadIdx.x;
    double acc = (double)logit[k];
    for (int t = 0; t < TTT; ++t)
        acc += (esum[t] / (double)EE) * (double)Wcls[DD + t];
    acc += (double)bcls[0];
    out[k] = (float)(1.0 / (1.0 + exp(-acc)));
}

extern "C" void kernel_launch(void* const* d_in, const int* in_sizes, int n_in,
                              void* d_out, int out_size, void* d_ws, size_t ws_size,
                              hipStream_t stream)
{
    const float* x_pkg   = (const float*)d_in[0];
    const float* x_dst   = (const float*)d_in[1];
    const int*   eindex  = (const int*)d_in[2];
    const float* eattr   = (const float*)d_in[3];
    const float* nmask   = (const float*)d_in[4];
    const float* emask   = (const float*)d_in[5];
    const float* W1s     = (const float*)d_in[6];
    const float* W1d     = (const float*)d_in[7];
    const float* a1      = (const float*)d_in[8];
    const float* W2s     = (const float*)d_in[9];
    const float* W2d     = (const float*)d_in[10];
    const float* a2      = (const float*)d_in[11];
    const float* Wassign = (const float*)d_in[12];
    const float* Wcls    = (const float*)d_in[13];
    const float* bcls    = (const float*)d_in[14];
    float* out = (float*)d_out;

    const int t = TTT - 1;  // only t=5 feeds h2[-1]; other 10 GAT layers are dead code
    const int* src5 = eindex + (size_t)t * 2 * EE;
    const int* dst5 = src5 + EE;
    const float* xdst5 = x_dst + (size_t)t * NN * DD;
    const float* W1s5 = W1s + (size_t)t * DD * HH * CC;
    const float* W1d5 = W1d + (size_t)t * DD * HH * CC;
    const float* a15  = a1 + (size_t)t * HH * CC;
    const float* W2s5 = W2s + (size_t)t * DD * HH * CC;
    const float* W2d5 = W2d + (size_t)t * DD * HH * CC;
    const float* a25  = a2 + (size_t)t * HH * CC;

    // ---- workspace carve: every buffer 256B-aligned ----
    // (round-2 crash root cause: esum double* landed on a 4B-odd offset ->
    //  misaligned atomicAdd(double) fault. Now all offsets are 256B multiples.)
    char* wsb = (char*)d_ws;
    size_t off = 0;
    auto carve = [&](size_t bytes) -> void* {
        void* p = wsb + off;
        off += (bytes + 255) & ~(size_t)255;
        return p;
    };
    float* hs     = (float*)carve((size_t)NN * DD * sizeof(float));
    float* hd     = (float*)carve((size_t)NN * DD * sizeof(float));
    float* hbuf   = (float*)carve((size_t)NN * DD * sizeof(float));
    int*   deg    = (int*)carve((size_t)NN * sizeof(int));
    int*   cursor = (int*)carve((size_t)NN * sizeof(int));
    int*   offs   = (int*)carve((size_t)(NN + 1) * sizeof(int));
    int*   eord   = (int*)carve((size_t)EE * sizeof(int));
    float* logit  = (float*)carve(KDIM * sizeof(float));
    double* esum  = (double*)carve(TTT * sizeof(double));

    dim3 ggrid((NN + GM - 1) / GM, DD / GN);
    int edge_node_blocks = (NN + 3) / 4;   // 1 wave per dst node
    int eb = (EE + 255) / 256;

    // ---- init + CSR build (dst graph shared by both layers) ----
    hipMemsetAsync(deg, 0, (size_t)NN * sizeof(int), stream);
    hipMemsetAsync(cursor, 0, (size_t)NN * sizeof(int), stream);
    hipMemsetAsync(logit, 0, KDIM * sizeof(float), stream);
    hipMemsetAsync(esum, 0, TTT * sizeof(double), stream);

    edge_mean_k<<<eb, 256, 0, stream>>>(eattr, esum, EE);
    count_k<<<eb, 256, 0, stream>>>(dst5, deg, EE);
    scan_k<<<1, 1024, 0, stream>>>(deg, offs);
    scatter_k<<<eb, 256, 0, stream>>>(dst5, offs, cursor, eord, EE);

    // ---- layer 1 (t=5) ----
    gemm128_k<<<ggrid, 256, 0, stream>>>(x_pkg, W1s5, hs, nmask, 0, NN);
    gemm128_k<<<ggrid, 256, 0, stream>>>(xdst5, W1d5, hd, nmask, 0, NN);
    edge_fused_k<<<edge_node_blocks, 256, 0, stream>>>(hs, hd, src5, emask, eord, offs, a15, hbuf);

    // ---- layer 2 ----
    gemm128_k<<<ggrid, 256, 0, stream>>>(hbuf, W2d5, hd, nullptr, 1, NN);
    gemm128_k<<<ggrid, 256, 0, stream>>>(x_pkg, W2s5, hs, nullptr, 1, NN);
    edge_fused_k<<<edge_node_blocks, 256, 0, stream>>>(hs, hd, src5, emask, eord, offs, a25, hbuf);

    // ---- fused assignment-softmax pooled classifier ----
    assign_reduce_k<<<(NN + AM - 1) / AM, 256, 0, stream>>>(hbuf, Wassign, Wcls, logit, NN);
    final_k<<<1, KDIM, 0, stream>>>(logit, esum, Wcls, bcls, out);
}

// Round 4
// 1192.905 us; speedup vs baseline: 1.9924x; 1.2086x over previous
//
#include <hip/hip_runtime.h>
#include <math.h>

#define NN 50000
#define EE 250000
#define TTT 6
#define DD 256
#define HH 4
#define CC 64
#define KDIM 64

// ---------------- fp32 tiled GEMM 128x128x16, 8x8 micro-tile ----------------
// C[n,m] = op(A[n,:]) @ B[:,m];  op=0: A row scaled by rowscale[n]; op=1: relu(A)
#define GM 128
#define GN 128
#define GK 16

__global__ __launch_bounds__(256) void gemm128_k(
    const float* __restrict__ A, const float* __restrict__ B,
    float* __restrict__ Cout, const float* __restrict__ rowscale,
    int op, int nrows)
{
    __shared__ __align__(16) float As[GK][GM + 4];
    __shared__ __align__(16) float Bs[GK][GN + 4];
    int tid = threadIdx.x;
    int row0 = blockIdx.x * GM;
    int col0 = blockIdx.y * GN;
    int tx = tid & 15, ty = tid >> 4;
    float acc[8][8] = {};
    for (int k0 = 0; k0 < DD; k0 += GK) {
        // stage A: 128 rows x 16 k = 512 float4
        #pragma unroll
        for (int li = 0; li < 2; ++li) {
            int i = tid + li * 256;
            int r = i >> 2;
            int kq = (i & 3) * 4;
            int gr = row0 + r;
            float4 v = make_float4(0.f, 0.f, 0.f, 0.f);
            if (gr < nrows) {
                v = *(const float4*)&A[(size_t)gr * DD + k0 + kq];
                if (op == 0) {
                    float s = rowscale[gr];
                    v.x *= s; v.y *= s; v.z *= s; v.w *= s;
                } else {
                    v.x = fmaxf(v.x, 0.f); v.y = fmaxf(v.y, 0.f);
                    v.z = fmaxf(v.z, 0.f); v.w = fmaxf(v.w, 0.f);
                }
            }
            As[kq + 0][r] = v.x; As[kq + 1][r] = v.y;
            As[kq + 2][r] = v.z; As[kq + 3][r] = v.w;
        }
        // stage B: 16 k x 128 cols = 512 float4
        #pragma unroll
        for (int li = 0; li < 2; ++li) {
            int i = tid + li * 256;
            int k = i >> 5;
            int m = (i & 31) * 4;
            *(float4*)&Bs[k][m] = *(const float4*)&B[(size_t)(k0 + k) * DD + col0 + m];
        }
        __syncthreads();
        #pragma unroll
        for (int kk = 0; kk < GK; ++kk) {
            float a[8], b[8];
            *(float4*)&a[0] = *(const float4*)&As[kk][ty * 4];
            *(float4*)&a[4] = *(const float4*)&As[kk][64 + ty * 4];
            *(float4*)&b[0] = *(const float4*)&Bs[kk][tx * 4];
            *(float4*)&b[4] = *(const float4*)&Bs[kk][64 + tx * 4];
            #pragma unroll
            for (int i2 = 0; i2 < 8; ++i2)
                #pragma unroll
                for (int j = 0; j < 8; ++j)
                    acc[i2][j] = fmaf(a[i2], b[j], acc[i2][j]);
        }
        __syncthreads();
    }
    #pragma unroll
    for (int i2 = 0; i2 < 8; ++i2) {
        int gr = row0 + ((i2 < 4) ? (ty * 4 + i2) : (64 + ty * 4 + (i2 - 4)));
        if (gr < nrows) {
            float4 o0 = {acc[i2][0], acc[i2][1], acc[i2][2], acc[i2][3]};
            float4 o1 = {acc[i2][4], acc[i2][5], acc[i2][6], acc[i2][7]};
            *(float4*)&Cout[(size_t)gr * DD + col0 + tx * 4] = o0;
            *(float4*)&Cout[(size_t)gr * DD + col0 + 64 + tx * 4] = o1;
        }
    }
}

// ---------------- CSR build: count, scan, scatter ----------------
__global__ __launch_bounds__(256) void count_k(const int* __restrict__ dst,
                                               int* __restrict__ deg, int nedges)
{
    int e = blockIdx.x * 256 + threadIdx.x;
    if (e < nedges) atomicAdd(&deg[dst[e]], 1);
}

__global__ __launch_bounds__(1024) void scan_k(const int* __restrict__ deg,
                                               int* __restrict__ offs)
{
    __shared__ int part[1024];
    int tid = threadIdx.x;
    const int CH = (NN + 1023) / 1024;
    int base = tid * CH;
    int s = 0;
    for (int i = 0; i < CH; ++i)
        if (base + i < NN) s += deg[base + i];
    part[tid] = s;
    __syncthreads();
    for (int off = 1; off < 1024; off <<= 1) {
        int v = (tid >= off) ? part[tid - off] : 0;
        __syncthreads();
        part[tid] += v;
        __syncthreads();
    }
    int run = part[tid] - s;   // exclusive prefix of this chunk
    for (int i = 0; i < CH; ++i) {
        if (base + i < NN) { offs[base + i] = run; run += deg[base + i]; }
    }
    if (tid == 1023) offs[NN] = part[1023];
}

__global__ __launch_bounds__(256) void scatter_k(const int* __restrict__ dst,
                                                 const int* __restrict__ offs,
                                                 int* __restrict__ cursor,
                                                 int* __restrict__ eord, int nedges)
{
    int e = blockIdx.x * 256 + threadIdx.x;
    if (e < nedges) {
        int d = dst[e];
        int p = atomicAdd(&cursor[d], 1);
        eord[offs[d] + p] = e;
    }
}

// ------------- fused GATv2 edge pass: one wave per dst node, no atomics -----
__global__ __launch_bounds__(256) void edge_fused_k(
    const float* __restrict__ hs, const float* __restrict__ hd,
    const int* __restrict__ src, const float* __restrict__ emask,
    const int* __restrict__ eord, const int* __restrict__ offs,
    const float* __restrict__ avec, float* __restrict__ hout)
{
    int lane = threadIdx.x & 63;
    int n = (int)((blockIdx.x * 256 + threadIdx.x) >> 6);
    if (n >= NN) return;
    float hdv[HH], av[HH], den[HH], accv[HH];
    #pragma unroll
    for (int h = 0; h < HH; ++h) {
        hdv[h] = hd[(size_t)n * DD + h * CC + lane];
        av[h] = avec[h * CC + lane];
        den[h] = 0.f; accv[h] = 0.f;
    }
    int b = offs[n], e2 = offs[n + 1];
    for (int idx = b; idx < e2; ++idx) {
        int e = eord[idx];
        int s = src[e];
        float ew = emask[e];
        const float* prs = hs + (size_t)s * DD;
        #pragma unroll
        for (int h = 0; h < HH; ++h) {
            float hsv = prs[h * CC + lane];
            float xx = hdv[h] + hsv;
            xx = xx > 0.f ? xx : 0.2f * xx;
            float v = av[h] * xx;
            #pragma unroll
            for (int off = 32; off; off >>= 1) v += __shfl_xor(v, off, 64);
            float p = expf(v);   // |e-score| small: exp safe; alpha identical w/o max-sub
            den[h] += p;
            accv[h] = fmaf(p * ew, hsv, accv[h]);
        }
    }
    #pragma unroll
    for (int h = 0; h < HH; ++h)
        hout[(size_t)n * DD + h * CC + lane] = accv[h] / (den[h] + 1e-16f);
}

// -------- per-timestep mean of edge_attr: 2-stage, NO contended atomics -----
// stage 1: 120 blocks grid-stride, per-block LDS tree reduce -> partial[b][t]
#define MBLK 120
__global__ __launch_bounds__(256) void edge_mean1_k(
    const float* __restrict__ eattr, double* __restrict__ partial, int nedges)
{
    __shared__ double sh[256];
    int tid = threadIdx.x;
    int stride = MBLK * 256;
    #pragma unroll
    for (int t = 0; t < TTT; ++t) {
        double a = 0.0;
        for (int i = blockIdx.x * 256 + tid; i < nedges; i += stride)
            a += (double)eattr[(size_t)t * nedges + i];
        sh[tid] = a;
        __syncthreads();
        #pragma unroll
        for (int s = 128; s; s >>= 1) {
            if (tid < s) sh[tid] += sh[tid + s];
            __syncthreads();
        }
        if (tid == 0) partial[(size_t)blockIdx.x * TTT + t] = sh[0];
        __syncthreads();
    }
}

// ---- fused assign-softmax + pooled classifier reduction --------------------
// logit[k] += sum_{n in tile} softmax_k(x[n]@Wa) * (x[n]@wcls)
#define AM 64
#define AK 32
__global__ __launch_bounds__(256) void assign_reduce_k(
    const float* __restrict__ x, const float* __restrict__ Wa,
    const float* __restrict__ wcls, float* __restrict__ logit_acc, int nrows)
{
    __shared__ __align__(16) float As[AK][AM + 4];
    __shared__ __align__(16) float Bs[AK][KDIM];
    __shared__ float wc[DD];
    __shared__ float Ps[AM][KDIM + 1];
    __shared__ float zp[4][AM];
    __shared__ float zsh[AM], rs[AM];
    int tid = threadIdx.x;
    int row0 = blockIdx.x * AM;
    int tx = tid & 15, ty = tid >> 4;
    for (int i = tid; i < DD; i += 256) wc[i] = wcls[i];
    float acc[4][4] = {};
    float zacc = 0.f;
    int node = tid & 63, part = tid >> 6;
    for (int k0 = 0; k0 < DD; k0 += AK) {
        for (int i = tid; i < AM * AK; i += 256) {
            int r = i / AK, k = i % AK;
            int gr = row0 + r;
            As[k][r] = (gr < nrows) ? x[(size_t)gr * DD + k0 + k] : 0.f;
        }
        for (int i = tid; i < AK * KDIM; i += 256) {
            int k = i >> 6, m = i & 63;
            Bs[k][m] = Wa[(size_t)(k0 + k) * KDIM + m];
        }
        __syncthreads();
        #pragma unroll
        for (int kk = 0; kk < AK; ++kk) {
            float4 a4 = *(const float4*)&As[kk][ty * 4];
            float4 b4 = *(const float4*)&Bs[kk][tx * 4];
            float av[4] = {a4.x, a4.y, a4.z, a4.w};
            float bv[4] = {b4.x, b4.y, b4.z, b4.w};
            #pragma unroll
            for (int i2 = 0; i2 < 4; ++i2)
                #pragma unroll
                for (int j = 0; j < 4; ++j)
                    acc[i2][j] = fmaf(av[i2], bv[j], acc[i2][j]);
        }
        #pragma unroll
        for (int kk = part * 8; kk < part * 8 + 8; ++kk)
            zacc = fmaf(As[kk][node], wc[k0 + kk], zacc);
        __syncthreads();
    }
    #pragma unroll
    for (int i2 = 0; i2 < 4; ++i2)
        #pragma unroll
        for (int j = 0; j < 4; ++j)
            Ps[ty * 4 + i2][tx * 4 + j] = acc[i2][j];
    zp[part][node] = zacc;
    __syncthreads();
    if (tid < AM) {
        float z = zp[0][tid] + zp[1][tid] + zp[2][tid] + zp[3][tid];
        zsh[tid] = z;
        float m = -1e30f;
        for (int k = 0; k < KDIM; ++k) m = fmaxf(m, Ps[tid][k]);
        float s = 0.f;
        for (int k = 0; k < KDIM; ++k) {
            float v = expf(Ps[tid][k] - m);
            Ps[tid][k] = v;
            s += v;
        }
        rs[tid] = s;
    }
    __syncthreads();
    if (tid < KDIM) {
        float t = 0.f;
        for (int n = 0; n < AM; ++n)
            t += Ps[n][tid] / rs[n] * zsh[n];
        atomicAdd(&logit_acc[tid], t);
    }
}

// -------- final: out[k] = sigmoid(logit[k] + agg_edge@Wcls[D:] + b) ---------
__global__ void final_k(const float* __restrict__ logit, const double* __restrict__ partial,
                        const float* __restrict__ Wcls, const float* __restrict__ bcls,
                        float* __restrict__ out)
{
    int k = threadIdx.x;
    double acc = (double)logit[k];
    #pragma unroll
    for (int t = 0; t < TTT; ++t) {
        double s = 0.0;
        for (int b = 0; b < MBLK; ++b) s += partial[(size_t)b * TTT + t];
        acc += (s / (double)EE) * (double)Wcls[DD + t];
    }
    acc += (double)bcls[0];
    out[k] = (float)(1.0 / (1.0 + exp(-acc)));
}

extern "C" void kernel_launch(void* const* d_in, const int* in_sizes, int n_in,
                              void* d_out, int out_size, void* d_ws, size_t ws_size,
                              hipStream_t stream)
{
    const float* x_pkg   = (const float*)d_in[0];
    const float* x_dst   = (const float*)d_in[1];
    const int*   eindex  = (const int*)d_in[2];
    const float* eattr   = (const float*)d_in[3];
    const float* nmask   = (const float*)d_in[4];
    const float* emask   = (const float*)d_in[5];
    const float* W1s     = (const float*)d_in[6];
    const float* W1d     = (const float*)d_in[7];
    const float* a1      = (const float*)d_in[8];
    const float* W2s     = (const float*)d_in[9];
    const float* W2d     = (const float*)d_in[10];
    const float* a2      = (const float*)d_in[11];
    const float* Wassign = (const float*)d_in[12];
    const float* Wcls    = (const float*)d_in[13];
    const float* bcls    = (const float*)d_in[14];
    float* out = (float*)d_out;

    const int t = TTT - 1;  // only t=5 feeds h2[-1]; other 10 GAT layers are dead code
    const int* src5 = eindex + (size_t)t * 2 * EE;
    const int* dst5 = src5 + EE;
    const float* xdst5 = x_dst + (size_t)t * NN * DD;
    const float* W1s5 = W1s + (size_t)t * DD * HH * CC;
    const float* W1d5 = W1d + (size_t)t * DD * HH * CC;
    const float* a15  = a1 + (size_t)t * HH * CC;
    const float* W2s5 = W2s + (size_t)t * DD * HH * CC;
    const float* W2d5 = W2d + (size_t)t * DD * HH * CC;
    const float* a25  = a2 + (size_t)t * HH * CC;

    // ---- workspace carve: every buffer 256B-aligned ----
    char* wsb = (char*)d_ws;
    size_t off = 0;
    auto carve = [&](size_t bytes) -> void* {
        void* p = wsb + off;
        off += (bytes + 255) & ~(size_t)255;
        return p;
    };
    float* hs     = (float*)carve((size_t)NN * DD * sizeof(float));
    float* hd     = (float*)carve((size_t)NN * DD * sizeof(float));
    float* hbuf   = (float*)carve((size_t)NN * DD * sizeof(float));
    int*   deg    = (int*)carve((size_t)NN * sizeof(int));
    int*   cursor = (int*)carve((size_t)NN * sizeof(int));
    int*   offs   = (int*)carve((size_t)(NN + 1) * sizeof(int));
    int*   eord   = (int*)carve((size_t)EE * sizeof(int));
    float* logit  = (float*)carve(KDIM * sizeof(float));
    double* partial = (double*)carve((size_t)MBLK * TTT * sizeof(double));

    dim3 ggrid((NN + GM - 1) / GM, DD / GN);
    int edge_node_blocks = (NN + 3) / 4;   // 1 wave per dst node
    int eb = (EE + 255) / 256;

    // ---- init + CSR build (dst graph shared by both layers) ----
    hipMemsetAsync(deg, 0, (size_t)NN * sizeof(int), stream);
    hipMemsetAsync(cursor, 0, (size_t)NN * sizeof(int), stream);
    hipMemsetAsync(logit, 0, KDIM * sizeof(float), stream);

    edge_mean1_k<<<MBLK, 256, 0, stream>>>(eattr, partial, EE);
    count_k<<<eb, 256, 0, stream>>>(dst5, deg, EE);
    scan_k<<<1, 1024, 0, stream>>>(deg, offs);
    scatter_k<<<eb, 256, 0, stream>>>(dst5, offs, cursor, eord, EE);

    // ---- layer 1 (t=5) ----
    gemm128_k<<<ggrid, 256, 0, stream>>>(x_pkg, W1s5, hs, nmask, 0, NN);
    gemm128_k<<<ggrid, 256, 0, stream>>>(xdst5, W1d5, hd, nmask, 0, NN);
    edge_fused_k<<<edge_node_blocks, 256, 0, stream>>>(hs, hd, src5, emask, eord, offs, a15, hbuf);

    // ---- layer 2 ----
    gemm128_k<<<ggrid, 256, 0, stream>>>(hbuf, W2d5, hd, nullptr, 1, NN);
    gemm128_k<<<ggrid, 256, 0, stream>>>(x_pkg, W2s5, hs, nullptr, 1, NN);
    edge_fused_k<<<edge_node_blocks, 256, 0, stream>>>(hs, hd, src5, emask, eord, offs, a25, hbuf);

    // ---- fused assignment-softmax pooled classifier ----
    assign_reduce_k<<<(NN + AM - 1) / AM, 256, 0, stream>>>(hbuf, Wassign, Wcls, logit, NN);
    final_k<<<1, KDIM, 0, stream>>>(logit, partial, Wcls, bcls, out);
}